// Round 1
// baseline (118187.244 us; speedup 1.0000x reference)
//
#include <hip/hip_runtime.h>
#include <math.h>

#define B_SZ 128
#define T_IN 8000
#define T_OUT 1600
#define HDIM 384
#define GDIM 1536   // 4*H
#define TC 40       // time chunk
#define NCHUNK (T_OUT / TC)   // 40
#define NTILES (12 * (B_SZ * TC / 128))   // 480 gemm tiles per chunk
#define NLB 32            // LSTM blocks (4 batch each)
#define NGB (256 - NLB)   // 224 gemm worker blocks

typedef _Float16 f16;
typedef __attribute__((ext_vector_type(2))) _Float16 f16x2;
typedef __attribute__((ext_vector_type(4))) _Float16 f16x4;
typedef __attribute__((ext_vector_type(8))) _Float16 f16x8;

__device__ inline float fdot2(f16x2 a, f16x2 b, float c) {
#if __has_builtin(__builtin_amdgcn_fdot2)
  return __builtin_amdgcn_fdot2(a, b, c, false);
#else
  return fmaf((float)a[0], (float)b[0], fmaf((float)a[1], (float)b[1], c));
#endif
}

__device__ inline float rcp_fast(float x) {
#if __has_builtin(__builtin_amdgcn_rcpf)
  return __builtin_amdgcn_rcpf(x);
#else
  return 1.f / x;
#endif
}
__device__ inline float sigf(float z) { return rcp_fast(1.f + __expf(-z)); }
__device__ inline float tanh_fast(float z) {
  z = fminf(fmaxf(z, -15.f), 15.f);
  float e = __expf(2.f * z);
  return (e - 1.f) * rcp_fast(e + 1.f);
}

// ---------------------------------------------------------------------------
// conv1 (5,1,4) + silu + conv2 (5,4,16) + silu, fused. One thread per (b,t).
// ---------------------------------------------------------------------------
__global__ __launch_bounds__(256) void conv12_kernel(
    const float* __restrict__ x, const float* __restrict__ w1, const float* __restrict__ b1,
    const float* __restrict__ w2, const float* __restrict__ b2, f16* __restrict__ y2) {
  __shared__ float sw1[20], sb1[4], sw2[320], sb2[16];
  int tid = threadIdx.x;
  if (tid < 20) sw1[tid] = w1[tid];
  if (tid < 4)  sb1[tid] = b1[tid];
  if (tid < 16) sb2[tid] = b2[tid];
  for (int i = tid; i < 320; i += 256) sw2[i] = w2[i];
  __syncthreads();
  int flat = blockIdx.x * 256 + tid;
  int b = flat / T_IN, t = flat % T_IN;
  const float* xb = x + (size_t)b * T_IN;
  float xv[9];
#pragma unroll
  for (int d = 0; d < 9; ++d) {
    int tt = t + d - 4;
    xv[d] = (tt >= 0 && tt < T_IN) ? xb[tt] : 0.f;
  }
  float y1[5][4];
#pragma unroll
  for (int u = 0; u < 5; ++u) {
    int tau = t + u - 2;
    bool valid = (tau >= 0 && tau < T_IN);
#pragma unroll
    for (int co = 0; co < 4; ++co) {
      float a = sb1[co];
#pragma unroll
      for (int k = 0; k < 5; ++k) a = fmaf(xv[u + k], sw1[k * 4 + co], a);
      y1[u][co] = valid ? (a / (1.f + expf(-a))) : 0.f;
    }
  }
  f16x8 o0, o1;
#pragma unroll
  for (int co = 0; co < 16; ++co) {
    float a = sb2[co];
#pragma unroll
    for (int u = 0; u < 5; ++u)
#pragma unroll
      for (int ci = 0; ci < 4; ++ci)
        a = fmaf(y1[u][ci], sw2[(u * 4 + ci) * 16 + co], a);
    float sv = a / (1.f + expf(-a));
    if (co < 8) o0[co] = (f16)sv; else o1[co - 8] = (f16)sv;
  }
  f16x8* dst = (f16x8*)(y2 + (size_t)flat * 16);
  dst[0] = o0;
  dst[1] = o1;
}

// ---------------------------------------------------------------------------
// conv3: (19,16,384), stride 5, SAME (pad 7/7), + silu. fp16 in/out, fp32 math.
// ---------------------------------------------------------------------------
__global__ __launch_bounds__(384) void conv3_kernel(
    const f16* __restrict__ y2, const float* __restrict__ w3, const float* __restrict__ b3,
    f16* __restrict__ act) {
  __shared__ float in_s[94 * 16];
  int tid = threadIdx.x;
  int b = blockIdx.y;
  int t0 = blockIdx.x * 16;
  int base_t = t0 * 5 - 7;
  for (int i = tid; i < 94 * 16; i += 384) {
    int tau = i >> 4, ci = i & 15;
    int tt = base_t + tau;
    in_s[i] = (tt >= 0 && tt < T_IN) ? (float)y2[((size_t)b * T_IN + tt) * 16 + ci] : 0.f;
  }
  __syncthreads();
  int c = tid;
  float acc[16];
  float bv = b3[c];
#pragma unroll
  for (int tt = 0; tt < 16; ++tt) acc[tt] = bv;
  for (int kk = 0; kk < 19; ++kk) {
#pragma unroll
    for (int c4 = 0; c4 < 4; ++c4) {
      float wa = w3[(size_t)((kk * 16 + c4 * 4 + 0) * 384) + c];
      float wb = w3[(size_t)((kk * 16 + c4 * 4 + 1) * 384) + c];
      float wc = w3[(size_t)((kk * 16 + c4 * 4 + 2) * 384) + c];
      float wd = w3[(size_t)((kk * 16 + c4 * 4 + 3) * 384) + c];
#pragma unroll
      for (int tt = 0; tt < 16; ++tt) {
        const float4 iv = *(const float4*)&in_s[(tt * 5 + kk) * 16 + c4 * 4];
        acc[tt] = fmaf(iv.x, wa, acc[tt]);
        acc[tt] = fmaf(iv.y, wb, acc[tt]);
        acc[tt] = fmaf(iv.z, wc, acc[tt]);
        acc[tt] = fmaf(iv.w, wd, acc[tt]);
      }
    }
  }
#pragma unroll
  for (int tt = 0; tt < 16; ++tt) {
    float a = acc[tt];
    a = a / (1.f + expf(-a));
    act[((size_t)b * T_OUT + t0 + tt) * HDIM + c] = (f16)a;
  }
}

// ---------------------------------------------------------------------------
// Wh repack: whP[l][k2][c] = (Wh[l][2k2][c], Wh[l][2k2+1][c]) as fp16x2.
// ---------------------------------------------------------------------------
__global__ __launch_bounds__(256) void whcvt_kernel(
    const float* __restrict__ Wh, f16x2* __restrict__ whP) {
  size_t idx = (size_t)blockIdx.x * 256 + threadIdx.x;
  int l = (int)(idx / (192 * 1536));
  int rem = (int)(idx % (192 * 1536));
  int k2 = rem / 1536;
  int c = rem % 1536;
  const float* src = Wh + ((size_t)l * 384 + 2 * k2) * 1536 + c;
  f16x2 v;
  v[0] = (f16)src[0];
  v[1] = (f16)src[1536];
  whP[idx] = v;
}

// ---------------------------------------------------------------------------
// Standalone chunked xg GEMM (primes chunk 0 of each layer).
// ---------------------------------------------------------------------------
__global__ __launch_bounds__(256) void gemm_xg_kernel(
    const f16* __restrict__ act, const float* __restrict__ Bw,
    f16* __restrict__ C, int lo) {
  __shared__ f16x2 As2[8 * 136];
  __shared__ f16x2 Bs2[8 * 128];
  int tid = threadIdx.x;
  int n0 = blockIdx.x * 128;
  int m0 = blockIdx.y * 128;
  int am = tid >> 2;
  int ak = (tid & 3) * 4;
  int bk = tid >> 5;
  int bn = (tid & 31) * 4;
  int row0 = m0 + am, row1 = row0 + 64;
  const f16* Ap0 = act + ((size_t)(row0 / TC) * T_OUT + lo + row0 % TC) * HDIM + ak;
  const f16* Ap1 = act + ((size_t)(row1 / TC) * T_OUT + lo + row1 % TC) * HDIM + ak;
  const float* Bp = Bw + (size_t)(2 * bk) * GDIM + n0 + bn;
  f16x4 ra0 = *(const f16x4*)Ap0;
  f16x4 ra1 = *(const f16x4*)Ap1;
  float4 rb0 = *(const float4*)Bp;
  float4 rb1 = *(const float4*)(Bp + (size_t)GDIM);
  float acc[8][8];
#pragma unroll
  for (int i = 0; i < 8; ++i)
#pragma unroll
    for (int j = 0; j < 8; ++j) acc[i][j] = 0.f;
  int tx = tid & 15, ty = tid >> 4;
  for (int kt = 0; kt < 24; ++kt) {
    int ak2 = ak >> 1;
    As2[(ak2 + 0) * 136 + am] = (f16x2){ra0[0], ra0[1]};
    As2[(ak2 + 1) * 136 + am] = (f16x2){ra0[2], ra0[3]};
    As2[(ak2 + 0) * 136 + am + 64] = (f16x2){ra1[0], ra1[1]};
    As2[(ak2 + 1) * 136 + am + 64] = (f16x2){ra1[2], ra1[3]};
    Bs2[bk * 128 + bn + 0] = (f16x2){(f16)rb0.x, (f16)rb1.x};
    Bs2[bk * 128 + bn + 1] = (f16x2){(f16)rb0.y, (f16)rb1.y};
    Bs2[bk * 128 + bn + 2] = (f16x2){(f16)rb0.z, (f16)rb1.z};
    Bs2[bk * 128 + bn + 3] = (f16x2){(f16)rb0.w, (f16)rb1.w};
    __syncthreads();
    if (kt < 23) {
      Ap0 += 16; Ap1 += 16; Bp += (size_t)16 * GDIM;
      ra0 = *(const f16x4*)Ap0;
      ra1 = *(const f16x4*)Ap1;
      rb0 = *(const float4*)Bp;
      rb1 = *(const float4*)(Bp + (size_t)GDIM);
    }
#pragma unroll
    for (int k2 = 0; k2 < 8; ++k2) {
      f16x8 a0 = *(const f16x8*)&As2[k2 * 136 + ty * 4];
      f16x8 a1 = *(const f16x8*)&As2[k2 * 136 + 64 + ty * 4];
      f16x8 b0 = *(const f16x8*)&Bs2[k2 * 128 + tx * 4];
      f16x8 b1 = *(const f16x8*)&Bs2[k2 * 128 + 64 + tx * 4];
      f16x2 av[8], bv[8];
#pragma unroll
      for (int q = 0; q < 4; ++q) {
        av[q] = (f16x2){a0[2 * q], a0[2 * q + 1]};
        av[q + 4] = (f16x2){a1[2 * q], a1[2 * q + 1]};
        bv[q] = (f16x2){b0[2 * q], b0[2 * q + 1]};
        bv[q + 4] = (f16x2){b1[2 * q], b1[2 * q + 1]};
      }
#pragma unroll
      for (int i = 0; i < 8; ++i)
#pragma unroll
        for (int j = 0; j < 8; ++j) acc[i][j] = fdot2(av[i], bv[j], acc[i][j]);
    }
    __syncthreads();
  }
#pragma unroll
  for (int i = 0; i < 8; ++i) {
    int mi = (i < 4) ? (ty * 4 + i) : (64 + ty * 4 + i - 4);
    f16* Cp = C + (size_t)(m0 + mi) * GDIM + n0;
    f16x4 p0, p1;
    p0[0] = (f16)acc[i][0]; p0[1] = (f16)acc[i][1]; p0[2] = (f16)acc[i][2]; p0[3] = (f16)acc[i][3];
    p1[0] = (f16)acc[i][4]; p1[1] = (f16)acc[i][5]; p1[2] = (f16)acc[i][6]; p1[3] = (f16)acc[i][7];
    *(f16x4*)(Cp + tx * 4) = p0;
    *(f16x4*)(Cp + 64 + tx * 4) = p1;
  }
}

// ---------------------------------------------------------------------------
// FUSED kernel: 256 blocks x 768 threads.
//  blocks 0..31  : LSTM chunk at lo_l, 4 batch elements per block. All of Wh
//                  is streamed from L2 each step through a 4-stage register
//                  pipeline (16 dwordx4 in flight/wave); 4-batch gives 2x
//                  fdot2 per streamed byte vs the old 64x2 layout. Per-block
//                  rotated k2 start offset desynchronizes the 32 identical
//                  L2 streams.
//  blocks 32..255: GEMM for next chunk at lo_g; 3 sub-tiles/block; invalid
//                  subs skip work (wave-uniform guard) but join barriers.
// ---------------------------------------------------------------------------
union FusedSh {
  struct { f16x2 h2s[4][192]; float zsp[2][4][1536]; float bias_s[1536]; } L;
  struct { f16x2 As2[3][8 * 136]; f16x2 Bs2[3][8 * 128]; } G;
  char pad[58368];
};

__global__ __launch_bounds__(768, 1) void fused_kernel(
    const f16* __restrict__ xgc_rd, f16* __restrict__ xgc_wr,
    const f16x2* __restrict__ whP, const float* __restrict__ bias,
    f16* __restrict__ act, float* __restrict__ cst, const float* __restrict__ Wi,
    int lo_l, int lo_g, int reverse, int first, int do_gemm) {
  __shared__ FusedSh sh;
  int tid = threadIdx.x;

  if (blockIdx.x < NLB) {
    // ================= LSTM branch: 4 batch / block =================
    int wid = blockIdx.x;
    int b0 = wid * 4;
    for (int i = tid; i < 1536; i += 768) sh.L.bias_s[i] = bias[i];
    int kap = tid / 384;          // K-half owned in dot phase (and pair-A batch)
    int cq = tid - kap * 384;     // gate column group (4 columns)
    int c4 = 4 * cq;
    int gj = cq;                  // hidden index in gate phase
    int blB = kap + 2;            // pair-B batch index
    float cA, cB;
    if (first) {
      cA = 0.f; cB = 0.f;
      ((f16x2*)sh.L.h2s)[tid] = (f16x2){(f16)0.f, (f16)0.f};
    } else {
      int tprev = reverse ? (lo_l + TC) : (lo_l - 1);
      cA = cst[(size_t)(b0 + kap) * HDIM + gj];
      cB = cst[(size_t)(b0 + blB) * HDIM + gj];
      ((f16*)&sh.L.h2s[kap][0])[gj] = act[((size_t)(b0 + kap) * T_OUT + tprev) * HDIM + gj];
      ((f16*)&sh.L.h2s[blB][0])[gj] = act[((size_t)(b0 + blB) * T_OUT + tprev) * HDIM + gj];
    }
    const f16x2* wcol = whP + c4 + (size_t)(96 * kap) * 1536;
    int qoff = (wid * 7) % 24;    // per-block stream rotation (fp reorder ok)
    __syncthreads();

    for (int s = 0; s < TC; ++s) {
      int t = reverse ? (lo_l + TC - 1 - s) : (lo_l + s);
      int tl = t - lo_l;
      // xg prefetch: independent of h, issue before the weight pipeline so
      // its L2 latency hides under the dot phase.
      const f16* xpA = xgc_rd + ((size_t)(b0 + kap) * TC + tl) * GDIM + gj;
      const f16* xpB = xgc_rd + ((size_t)(b0 + blB) * TC + tl) * GDIM + gj;
      float xA0 = (float)xpA[0], xA1 = (float)xpA[384], xA2 = (float)xpA[768], xA3 = (float)xpA[1152];
      float xB0 = (float)xpB[0], xB1 = (float)xpB[384], xB2 = (float)xpB[768], xB3 = (float)xpB[1152];

      float acc0[4] = {0.f, 0.f, 0.f, 0.f}, acc1[4] = {0.f, 0.f, 0.f, 0.f};
      float acc2[4] = {0.f, 0.f, 0.f, 0.f}, acc3[4] = {0.f, 0.f, 0.f, 0.f};

      auto loadw = [&](f16x8& s0, f16x8& s1, f16x8& s2, f16x8& s3, int p) {
        int qr = p + qoff; if (qr >= 24) qr -= 24;
        const f16x2* wp = wcol + (size_t)(4 * qr) * 1536;
        s0 = *(const f16x8*)(wp);
        s1 = *(const f16x8*)(wp + 1536);
        s2 = *(const f16x8*)(wp + 2 * 1536);
        s3 = *(const f16x8*)(wp + 3 * 1536);
      };
      auto compw = [&](f16x8 s0, f16x8 s1, f16x8 s2, f16x8 s3, int p) {
        int qr = p + qoff; if (qr >= 24) qr -= 24;
        int k2b = 96 * kap + 4 * qr;
        f16x8 h0 = *(const f16x8*)&sh.L.h2s[0][k2b];
        f16x8 h1 = *(const f16x8*)&sh.L.h2s[1][k2b];
        f16x8 h2 = *(const f16x8*)&sh.L.h2s[2][k2b];
        f16x8 h3 = *(const f16x8*)&sh.L.h2s[3][k2b];
#pragma unroll
        for (int c = 0; c < 4; ++c) {
          f16x2 w0 = {s0[2 * c], s0[2 * c + 1]};
          f16x2 w1 = {s1[2 * c], s1[2 * c + 1]};
          f16x2 w2 = {s2[2 * c], s2[2 * c + 1]};
          f16x2 w3 = {s3[2 * c], s3[2 * c + 1]};
          acc0[c] = fdot2(w0, (f16x2){h0[0], h0[1]}, acc0[c]);
          acc0[c] = fdot2(w1, (f16x2){h0[2], h0[3]}, acc0[c]);
          acc0[c] = fdot2(w2, (f16x2){h0[4], h0[5]}, acc0[c]);
          acc0[c] = fdot2(w3, (f16x2){h0[6], h0[7]}, acc0[c]);
          acc1[c] = fdot2(w0, (f16x2){h1[0], h1[1]}, acc1[c]);
          acc1[c] = fdot2(w1, (f16x2){h1[2], h1[3]}, acc1[c]);
          acc1[c] = fdot2(w2, (f16x2){h1[4], h1[5]}, acc1[c]);
          acc1[c] = fdot2(w3, (f16x2){h1[6], h1[7]}, acc1[c]);
          acc2[c] = fdot2(w0, (f16x2){h2[0], h2[1]}, acc2[c]);
          acc2[c] = fdot2(w1, (f16x2){h2[2], h2[3]}, acc2[c]);
          acc2[c] = fdot2(w2, (f16x2){h2[4], h2[5]}, acc2[c]);
          acc2[c] = fdot2(w3, (f16x2){h2[6], h2[7]}, acc2[c]);
          acc3[c] = fdot2(w0, (f16x2){h3[0], h3[1]}, acc3[c]);
          acc3[c] = fdot2(w1, (f16x2){h3[2], h3[3]}, acc3[c]);
          acc3[c] = fdot2(w2, (f16x2){h3[4], h3[5]}, acc3[c]);
          acc3[c] = fdot2(w3, (f16x2){h3[6], h3[7]}, acc3[c]);
        }
      };

      // 4-stage software pipeline: loads run 4 q-iterations ahead of use.
      f16x8 wa0, wa1, wa2, wa3, wb0, wb1, wb2, wb3;
      f16x8 wc0, wc1, wc2, wc3, wd0, wd1, wd2, wd3;
      loadw(wa0, wa1, wa2, wa3, 0);
      loadw(wb0, wb1, wb2, wb3, 1);
      loadw(wc0, wc1, wc2, wc3, 2);
      loadw(wd0, wd1, wd2, wd3, 3);
      for (int p = 0; p < 20; p += 4) {
        compw(wa0, wa1, wa2, wa3, p);     loadw(wa0, wa1, wa2, wa3, p + 4);
        compw(wb0, wb1, wb2, wb3, p + 1); loadw(wb0, wb1, wb2, wb3, p + 5);
        compw(wc0, wc1, wc2, wc3, p + 2); loadw(wc0, wc1, wc2, wc3, p + 6);
        compw(wd0, wd1, wd2, wd3, p + 3); loadw(wd0, wd1, wd2, wd3, p + 7);
      }
      compw(wa0, wa1, wa2, wa3, 20);
      compw(wb0, wb1, wb2, wb3, 21);
      compw(wc0, wc1, wc2, wc3, 22);
      compw(wd0, wd1, wd2, wd3, 23);

      *(float4*)&sh.L.zsp[kap][0][c4] = make_float4(acc0[0], acc0[1], acc0[2], acc0[3]);
      *(float4*)&sh.L.zsp[kap][1][c4] = make_float4(acc1[0], acc1[1], acc1[2], acc1[3]);
      *(float4*)&sh.L.zsp[kap][2][c4] = make_float4(acc2[0], acc2[1], acc2[2], acc2[3]);
      *(float4*)&sh.L.zsp[kap][3][c4] = make_float4(acc3[0], acc3[1], acc3[2], acc3[3]);
      __syncthreads();
      {
        float ziA = sh.L.zsp[0][kap][gj]        + sh.L.zsp[1][kap][gj]        + sh.L.bias_s[gj]        + xA0;
        float zfA = sh.L.zsp[0][kap][384 + gj]  + sh.L.zsp[1][kap][384 + gj]  + sh.L.bias_s[384 + gj]  + xA1;
        float zgA = sh.L.zsp[0][kap][768 + gj]  + sh.L.zsp[1][kap][768 + gj]  + sh.L.bias_s[768 + gj]  + xA2;
        float zoA = sh.L.zsp[0][kap][1152 + gj] + sh.L.zsp[1][kap][1152 + gj] + sh.L.bias_s[1152 + gj] + xA3;
        float ziB = sh.L.zsp[0][blB][gj]        + sh.L.zsp[1][blB][gj]        + sh.L.bias_s[gj]        + xB0;
        float zfB = sh.L.zsp[0][blB][384 + gj]  + sh.L.zsp[1][blB][384 + gj]  + sh.L.bias_s[384 + gj]  + xB1;
        float zgB = sh.L.zsp[0][blB][768 + gj]  + sh.L.zsp[1][blB][768 + gj]  + sh.L.bias_s[768 + gj]  + xB2;
        float zoB = sh.L.zsp[0][blB][1152 + gj] + sh.L.zsp[1][blB][1152 + gj] + sh.L.bias_s[1152 + gj] + xB3;
        float igA = sigf(ziA), fgA = sigf(zfA), gvA = tanh_fast(zgA), ogA = sigf(zoA);
        float igB = sigf(ziB), fgB = sigf(zfB), gvB = tanh_fast(zgB), ogB = sigf(zoB);
        cA = fgA * cA + igA * gvA;
        cB = fgB * cB + igB * gvB;
        float hvA = ogA * tanh_fast(cA);
        float hvB = ogB * tanh_fast(cB);
        f16 hA = (f16)hvA, hB = (f16)hvB;
        ((f16*)&sh.L.h2s[kap][0])[gj] = hA;
        ((f16*)&sh.L.h2s[blB][0])[gj] = hB;
        act[((size_t)(b0 + kap) * T_OUT + t) * HDIM + gj] = hA;
        act[((size_t)(b0 + blB) * T_OUT + t) * HDIM + gj] = hB;
      }
      __syncthreads();
    }
    cst[(size_t)(b0 + kap) * HDIM + gj] = cA;
    cst[(size_t)(b0 + blB) * HDIM + gj] = cB;
  } else {
    // ================= GEMM worker branch =================
    if (!do_gemm) return;
    int wid = blockIdx.x - NLB;       // 0..223
    int sub = tid >> 8;               // 0..2 (wave-uniform)
    int stid = tid & 255;
    int tileid = wid + NGB * sub;     // 0..671
    bool valid = (tileid < NTILES);
    int tclamp = valid ? tileid : 0;
    int n0 = (tclamp % 12) * 128;
    int m0 = (tclamp / 12) * 128;
    f16x2* As2 = &sh.G.As2[sub][0];
    f16x2* Bs2 = &sh.G.Bs2[sub][0];
    int am = stid >> 2;
    int ak = (stid & 3) * 4;
    int bk = stid >> 5;
    int bn = (stid & 31) * 4;
    int row0 = m0 + am, row1 = row0 + 64;
    const f16* Ap0 = act + ((size_t)(row0 / TC) * T_OUT + lo_g + row0 % TC) * HDIM + ak;
    const f16* Ap1 = act + ((size_t)(row1 / TC) * T_OUT + lo_g + row1 % TC) * HDIM + ak;
    const float* Bp = Wi + (size_t)(2 * bk) * GDIM + n0 + bn;
    f16x4 ra0 = {}, ra1 = {};
    float4 rb0 = {}, rb1 = {};
    if (valid) {
      ra0 = *(const f16x4*)Ap0;
      ra1 = *(const f16x4*)Ap1;
      rb0 = *(const float4*)Bp;
      rb1 = *(const float4*)(Bp + (size_t)GDIM);
    }
    float acc[8][8];
#pragma unroll
    for (int i = 0; i < 8; ++i)
#pragma unroll
      for (int j = 0; j < 8; ++j) acc[i][j] = 0.f;
    int tx = stid & 15, ty = stid >> 4;
    for (int kt = 0; kt < 24; ++kt) {
      if (valid) {
        int ak2 = ak >> 1;
        As2[(ak2 + 0) * 136 + am] = (f16x2){ra0[0], ra0[1]};
        As2[(ak2 + 1) * 136 + am] = (f16x2){ra0[2], ra0[3]};
        As2[(ak2 + 0) * 136 + am + 64] = (f16x2){ra1[0], ra1[1]};
        As2[(ak2 + 1) * 136 + am + 64] = (f16x2){ra1[2], ra1[3]};
        Bs2[bk * 128 + bn + 0] = (f16x2){(f16)rb0.x, (f16)rb1.x};
        Bs2[bk * 128 + bn + 1] = (f16x2){(f16)rb0.y, (f16)rb1.y};
        Bs2[bk * 128 + bn + 2] = (f16x2){(f16)rb0.z, (f16)rb1.z};
        Bs2[bk * 128 + bn + 3] = (f16x2){(f16)rb0.w, (f16)rb1.w};
      }
      __syncthreads();
      if (valid) {
        if (kt < 23) {
          Ap0 += 16; Ap1 += 16; Bp += (size_t)16 * GDIM;
          ra0 = *(const f16x4*)Ap0;
          ra1 = *(const f16x4*)Ap1;
          rb0 = *(const float4*)Bp;
          rb1 = *(const float4*)(Bp + (size_t)GDIM);
        }
#pragma unroll
        for (int k2 = 0; k2 < 8; ++k2) {
          f16x8 a0 = *(const f16x8*)&As2[k2 * 136 + ty * 4];
          f16x8 a1 = *(const f16x8*)&As2[k2 * 136 + 64 + ty * 4];
          f16x8 b0 = *(const f16x8*)&Bs2[k2 * 128 + tx * 4];
          f16x8 b1 = *(const f16x8*)&Bs2[k2 * 128 + 64 + tx * 4];
          f16x2 av[8], bv[8];
#pragma unroll
          for (int q = 0; q < 4; ++q) {
            av[q] = (f16x2){a0[2 * q], a0[2 * q + 1]};
            av[q + 4] = (f16x2){a1[2 * q], a1[2 * q + 1]};
            bv[q] = (f16x2){b0[2 * q], b0[2 * q + 1]};
            bv[q + 4] = (f16x2){b1[2 * q], b1[2 * q + 1]};
          }
#pragma unroll
          for (int i = 0; i < 8; ++i)
#pragma unroll
            for (int j = 0; j < 8; ++j) acc[i][j] = fdot2(av[i], bv[j], acc[i][j]);
        }
      }
      __syncthreads();
    }
    if (valid) {
#pragma unroll
      for (int i = 0; i < 8; ++i) {
        int mi = (i < 4) ? (ty * 4 + i) : (64 + ty * 4 + i - 4);
        f16* Cp = xgc_wr + (size_t)(m0 + mi) * GDIM + n0;
        f16x4 p0, p1;
        p0[0] = (f16)acc[i][0]; p0[1] = (f16)acc[i][1]; p0[2] = (f16)acc[i][2]; p0[3] = (f16)acc[i][3];
        p1[0] = (f16)acc[i][4]; p1[1] = (f16)acc[i][5]; p1[2] = (f16)acc[i][6]; p1[3] = (f16)acc[i][7];
        *(f16x4*)(Cp + tx * 4) = p0;
        *(f16x4*)(Cp + 64 + tx * 4) = p1;
      }
    }
  }
}

// ---------------------------------------------------------------------------
// dense: out(204800,5) = h(204800,384 fp16) @ W(384,5) + b  (fp32 out)
// ---------------------------------------------------------------------------
__global__ __launch_bounds__(256) void dense_kernel(
    const f16* __restrict__ h, const float* __restrict__ dw,
    const float* __restrict__ db, float* __restrict__ out) {
  __shared__ float ws_[1920];
  __shared__ float bs[5];
  int tid = threadIdx.x;
  for (int i = tid; i < 1920; i += 256) ws_[i] = dw[i];
  if (tid < 5) bs[tid] = db[tid];
  __syncthreads();
  size_t flat = (size_t)blockIdx.x * 256 + tid;
  const f16* hp = h + flat * HDIM;
  float acc[5];
#pragma unroll
  for (int o = 0; o < 5; ++o) acc[o] = bs[o];
  for (int d = 0; d < HDIM; d += 4) {
    f16x4 hv = *(const f16x4*)(hp + d);
#pragma unroll
    for (int o = 0; o < 5; ++o) {
      acc[o] = fmaf((float)hv[0], ws_[(d + 0) * 5 + o], acc[o]);
      acc[o] = fmaf((float)hv[1], ws_[(d + 1) * 5 + o], acc[o]);
      acc[o] = fmaf((float)hv[2], ws_[(d + 2) * 5 + o], acc[o]);
      acc[o] = fmaf((float)hv[3], ws_[(d + 3) * 5 + o], acc[o]);
    }
  }
  float* op = out + flat * 5;
#pragma unroll
  for (int o = 0; o < 5; ++o) op[o] = acc[o];
}

// ---------------------------------------------------------------------------
extern "C" void kernel_launch(void* const* d_in, const int* in_sizes, int n_in,
                              void* d_out, int out_size, void* d_ws, size_t ws_size,
                              hipStream_t stream) {
  const float* x  = (const float*)d_in[0];
  const float* w1 = (const float*)d_in[1];
  const float* b1 = (const float*)d_in[2];
  const float* w2 = (const float*)d_in[3];
  const float* b2 = (const float*)d_in[4];
  const float* w3 = (const float*)d_in[5];
  const float* b3 = (const float*)d_in[6];
  const float* Wi = (const float*)d_in[7];
  const float* Wh = (const float*)d_in[8];
  const float* lb = (const float*)d_in[9];
  const float* dw = (const float*)d_in[10];
  const float* db = (const float*)d_in[11];
  float* out = (float*)d_out;
  char* ws = (char*)d_ws;

  // ws (~194.8 MB <= proven 197): act | xgcA | xgcB | whP | cst
  const size_t ACT_BYTES = (size_t)B_SZ * T_OUT * HDIM * 2;   // 157.3 MB
  const size_t XGC_BYTES = (size_t)B_SZ * TC * GDIM * 2;      // 15.7 MB each
  const size_t WHP_BYTES = (size_t)5 * 192 * 1536 * 4;        // 5.9 MB
  f16*   act  = (f16*)ws;
  f16*   xgcA = (f16*)(ws + ACT_BYTES);
  f16*   xgcB = (f16*)(ws + ACT_BYTES + XGC_BYTES);
  f16x2* whP  = (f16x2*)(ws + ACT_BYTES + 2 * XGC_BYTES);
  float* cst  = (float*)(ws + ACT_BYTES + 2 * XGC_BYTES + WHP_BYTES);
  f16* y2 = xgcA;  // alias: consumed before xgc/whP are written

  hipLaunchKernelGGL(conv12_kernel, dim3(B_SZ * T_IN / 256), dim3(256), 0, stream,
                     x, w1, b1, w2, b2, y2);
  hipLaunchKernelGGL(conv3_kernel, dim3(T_OUT / 16, B_SZ), dim3(384), 0, stream,
                     y2, w3, b3, act);
  hipLaunchKernelGGL(whcvt_kernel, dim3(5 * 192 * 1536 / 256), dim3(256), 0, stream,
                     Wh, whP);

  for (int l = 0; l < 5; ++l) {
    int rev = (l % 2 == 0) ? 1 : 0;
    const float* wi_p = Wi + (size_t)l * HDIM * GDIM;
    const f16x2* wh_p = whP + (size_t)l * 192 * 1536;
    const float* lb_p = lb + (size_t)l * GDIM;
    int lo0 = rev ? (T_OUT - TC) : 0;
    hipLaunchKernelGGL(gemm_xg_kernel, dim3(GDIM / 128, (B_SZ * TC) / 128), dim3(256), 0, stream,
                       act, wi_p, xgcA, lo0);
    for (int ci = 0; ci < NCHUNK; ++ci) {
      int lo_l = rev ? (T_OUT - (ci + 1) * TC) : (ci * TC);
      int do_gemm = (ci + 1 < NCHUNK) ? 1 : 0;
      int lo_g = do_gemm ? (rev ? (T_OUT - (ci + 2) * TC) : ((ci + 1) * TC)) : 0;
      f16* rd = (ci % 2 == 0) ? xgcA : xgcB;
      f16* wr = (ci % 2 == 0) ? xgcB : xgcA;
      hipLaunchKernelGGL(fused_kernel, dim3(256), dim3(768), 0, stream,
                         rd, wr, wh_p, lb_p, act, cst, wi_p,
                         lo_l, lo_g, rev, (ci == 0) ? 1 : 0, do_gemm);
    }
  }
  hipLaunchKernelGGL(dense_kernel, dim3((B_SZ * T_OUT) / 256), dim3(256), 0, stream,
                     act, dw, db, out);
}